// Round 1
// baseline (1455.451 us; speedup 1.0000x reference)
//
#include <hip/hip_runtime.h>

// LIIF render, fully fused, fp16 MFMA. Round 4: register software-pipelining.
// Round-3 diagnosis: HBM at 1% of peak; MfmaUtil 33.9% == exactly the
// serialized-schedule prediction (MFMA floor ~228us vs 606us measured).
// Occupancy is LDS-bound at 2 blocks/CU -> only 2 waves/SIMD of TLP, and the
// single-buffered k-loop exposed ~120cy ds_read + 200-400cy L2 weight-load
// latency every k-step (loads sat AFTER the MFMA burst in program order and
// reused the same VGPRs -> WAR serialization).
// Changes (scheduling only, no layout/numerics changes):
//  - k-loop fully unrolled (KSTEPS template const) with explicit 2-deep
//    register double-buffers for A (L2 weights) and B (LDS activations);
//    prefetch of step s+1 issues BEFORE the 32-MFMA burst of step s.
//    VGPRs are free: LDS caps us at 2 waves/SIMD, so up to 256 VGPR costs
//    no occupancy.
//  - bias float4 loads hoisted out of the barrier-critical write phase
//    (issued before __syncthreads, consumed after).
//  - s_setprio(1) around MFMA bursts: the 2 co-resident blocks run at
//    unsynchronized phases, so priority arbitration has something to do.

typedef _Float16 f16;
typedef _Float16 f16x8 __attribute__((ext_vector_type(8)));
typedef _Float16 f16x4 __attribute__((ext_vector_type(4)));
typedef float    f32x4 __attribute__((ext_vector_type(4)));

#define MFMA(a, b, c) __builtin_amdgcn_mfma_f32_16x16x32_f16((a), (b), (c), 0, 0, 0)

constexpr int HF = 64, WF = 64;         // feature map dims
constexpr int HO = 256, WO = 256;       // output dims
constexpr int Q = HO * WO;              // 65536 queries per image
constexpr int D = 256;                  // hidden width
constexpr int K0P = 96;                 // input dim 68 padded to 96 (3 k-steps)
constexpr int STR = 264;                // LDS row stride (halves)
constexpr int R = 128;                  // query rows per block

// workspace layout (bytes)
constexpr size_t OFF_FEAT = 0;                        // 4*4096*64*2 = 2 MiB
constexpr size_t OFF_W0   = 2097152;                  // 256*96*2
constexpr size_t OFF_W1   = OFF_W0 + 256 * 96 * 2;    // 256*256*2
constexpr size_t OFF_W2   = OFF_W1 + 256 * 256 * 2;
constexpr size_t OFF_W3   = OFF_W2 + 256 * 256 * 2;
constexpr size_t OFF_W4   = OFF_W3 + 256 * 256 * 2;   // 16*256*2

// (N,C,Hf,Wf) fp32 -> (N, Hf*Wf, C) fp16 so a gather row is 128 B contiguous.
__global__ void prep_feat(const float* __restrict__ f, f16* __restrict__ ft) {
  int idx = blockIdx.x * 256 + threadIdx.x;          // 1,048,576 total
  int c = idx & 63, p = (idx >> 6) & 4095, n = idx >> 18;
  ft[idx] = (f16)f[((((size_t)n << 6) | c) << 12) | p];
}

// w (K x N) fp32 -> wt (Npad x Kpad) fp16, zero-padded.
__global__ void prep_w(const float* __restrict__ w, f16* __restrict__ wt,
                       int K, int N, int Kpad, int Npad) {
  int idx = blockIdx.x * 256 + threadIdx.x;
  if (idx >= Npad * Kpad) return;
  int k = idx % Kpad, n = idx / Kpad;
  wt[idx] = (f16)((k < K && n < N) ? w[k * N + n] : 0.0f);
}

// Geometry for query q, tap (vx, vy): feature pixel p and rel coords.
__device__ __forceinline__ void tap_geom(int q, float vx, float vy,
                                         int& p, float& rel0, float& rel1) {
  int qy = q >> 8, qx = q & (WO - 1);
  float cy0 = (float)(2 * qy + 1) * (1.0f / HO) - 1.0f;
  float cx0 = (float)(2 * qx + 1) * (1.0f / WO) - 1.0f;
  float cy = cy0 + vx * (1.0f / HF) + 1e-6f;
  float cx = cx0 + vy * (1.0f / WF) + 1e-6f;
  cy = fminf(fmaxf(cy, -1.0f + 1e-6f), 1.0f - 1e-6f);
  cx = fminf(fmaxf(cx, -1.0f + 1e-6f), 1.0f - 1e-6f);
  int iy = (int)rintf(((cy + 1.0f) * (float)HF - 1.0f) * 0.5f);  // rndne == jnp.round
  int ix = (int)rintf(((cx + 1.0f) * (float)WF - 1.0f) * 0.5f);
  iy = min(max(iy, 0), HF - 1);
  ix = min(max(ix, 0), WF - 1);
  p = (iy << 6) | ix;
  rel0 = (cy0 - ((float)(2 * iy + 1) * (1.0f / HF) - 1.0f)) * (float)HF;
  rel1 = (cx0 - ((float)(2 * ix + 1) * (1.0f / WF) - 1.0f)) * (float)WF;
}

// Blend weight for tap t, query q: preds[t] pairs with areas[3-t].
__device__ __forceinline__ float blend_wt(int q, int t) {
  float a[4], tot = 0.0f;
#pragma unroll
  for (int u = 0; u < 4; ++u) {
    int p; float r0, r1;
    tap_geom(q, (u & 2) ? 1.0f : -1.0f, (u & 1) ? 1.0f : -1.0f, p, r0, r1);
    a[u] = fabsf(r0 * r1) + 1e-9f;
    tot += a[u];
  }
  float sel = (t == 0) ? a[3] : (t == 1) ? a[2] : (t == 2) ? a[1] : a[0];
  return sel / tot;
}

// One hidden layer on the shared 128-row tile, in place.
// m = out-feature (this wave owns feats [wv*64, wv*64+64)), n = query rows.
// A = W^T (Npad x KPAD, global), B = X (query-major LDS).
// Fully unrolled k-loop with 2-deep register double-buffering: loads for
// step s+1 issue before the MFMA burst of step s (no WAR on operand regs,
// L2/LDS latency hides under the ~620cy burst).
template <int KSTEPS, int KPAD>
__device__ __forceinline__ void mlp_layer(f16* X, const f16* __restrict__ wt,
                                          const float* __restrict__ bv,
                                          int wv, int col, int quad) {
  f32x4 acc[4][8];
#pragma unroll
  for (int mt = 0; mt < 4; ++mt)
#pragma unroll
    for (int nt = 0; nt < 8; ++nt) acc[mt][nt] = 0.0f;

  const f16* ap = wt + (wv * 64 + col) * KPAD + quad * 8;  // A[m=col+16mt][k]
  const f16* bp = X + col * STR + quad * 8;                // B[n=col+16nt][k]

  f16x8 a[2][4], b[2][8];
#pragma unroll
  for (int mt = 0; mt < 4; ++mt)
    a[0][mt] = *(const f16x8*)(ap + mt * 16 * KPAD);
#pragma unroll
  for (int nt = 0; nt < 8; ++nt)
    b[0][nt] = *(const f16x8*)(bp + nt * 16 * STR);

#pragma unroll
  for (int s = 0; s < KSTEPS; ++s) {
    const int cur = s & 1, nxt = cur ^ 1;       // compile-time after unroll
    if (s + 1 < KSTEPS) {
#pragma unroll
      for (int mt = 0; mt < 4; ++mt)
        a[nxt][mt] = *(const f16x8*)(ap + (s + 1) * 32 + mt * 16 * KPAD);
#pragma unroll
      for (int nt = 0; nt < 8; ++nt)
        b[nxt][nt] = *(const f16x8*)(bp + (s + 1) * 32 + nt * 16 * STR);
    }
    __builtin_amdgcn_s_setprio(1);
#pragma unroll
    for (int mt = 0; mt < 4; ++mt)
#pragma unroll
      for (int nt = 0; nt < 8; ++nt)
        acc[mt][nt] = MFMA(a[cur][mt], b[cur][nt], acc[mt][nt]);
    __builtin_amdgcn_s_setprio(0);
  }

  // Bias preload: issued before the barrier so L2 latency hides under the
  // barrier wait instead of sitting inside the write phase.
  float4 bb[4];
#pragma unroll
  for (int mt = 0; mt < 4; ++mt)
    bb[mt] = *(const float4*)(bv + wv * 64 + mt * 16 + quad * 4);

  __syncthreads();   // all reads of X done before overwrite
  // D: row(m=feat) = mt*16 + quad*4 + i, col(n=query) = nt*16 + col.
  // Lane holds 4 consecutive feats -> vectorized b64 LDS writes.
#pragma unroll
  for (int mt = 0; mt < 4; ++mt) {
#pragma unroll
    for (int nt = 0; nt < 8; ++nt) {
      f16x4 y;
      y[0] = (f16)fmaxf(acc[mt][nt][0] + bb[mt].x, 0.0f);
      y[1] = (f16)fmaxf(acc[mt][nt][1] + bb[mt].y, 0.0f);
      y[2] = (f16)fmaxf(acc[mt][nt][2] + bb[mt].z, 0.0f);
      y[3] = (f16)fmaxf(acc[mt][nt][3] + bb[mt].w, 0.0f);
      *(f16x4*)(X + (nt * 16 + col) * STR + wv * 64 + mt * 16 + quad * 4) = y;
    }
  }
  __syncthreads();
}

__global__ __launch_bounds__(256, 2) void liif_main(
    const f16* __restrict__ featT,
    const f16* __restrict__ wt0, const f16* __restrict__ wt1,
    const f16* __restrict__ wt2, const f16* __restrict__ wt3,
    const f16* __restrict__ wt4,
    const float* __restrict__ b0, const float* __restrict__ b1,
    const float* __restrict__ b2, const float* __restrict__ b3,
    const float* __restrict__ b4, float* __restrict__ out) {
  __shared__ __attribute__((aligned(16))) f16 X[R * STR];   // 67.6 KB
  const int tid = threadIdx.x;
  const int wv = tid >> 6;
  const int lane = tid & 63;
  const int row0 = blockIdx.x * R;               // rows = n*Q + q, 128 per block
  const int n = row0 >> 16;
  const int q0 = row0 & (Q - 1);
  const int col = lane & 15, quad = lane >> 4;

  float oacc[2][4] = {{0, 0, 0, 0}, {0, 0, 0, 0}};
  float bias4[4];
#pragma unroll
  for (int i = 0; i < 4; ++i) bias4[i] = (i < 3) ? b4[i] : 0.0f;

#pragma unroll 1
  for (int t = 0; t < 4; ++t) {
    const float vx = (t & 2) ? 1.0f : -1.0f;
    const float vy = (t & 1) ? 1.0f : -1.0f;

    __syncthreads();   // previous tap's reads of X complete
    // ---- gather X0: 64 feat + rel(2) + rel_cell(2), pad to 96 ----
    {
      const int gr = tid >> 1, hf = tid & 1;   // 2 threads per row, 64 B each
      int p; float r0, r1;
      tap_geom(q0 + gr, vx, vy, p, r0, r1);
      const f16x8* src = (const f16x8*)(featT + (((size_t)n << 12) + p) * 64 + hf * 32);
      f16x8* dst = (f16x8*)(X + gr * STR + hf * 32);
      dst[0] = src[0]; dst[1] = src[1]; dst[2] = src[2]; dst[3] = src[3];
      if (tid < R) {
        int p2; float s0, s1;
        tap_geom(q0 + tid, vx, vy, p2, s0, s1);
        f16* xr = X + tid * STR;
        f16x4 relv = {(f16)s0, (f16)s1, (f16)0.5f, (f16)0.5f};
        *(f16x4*)(xr + 64) = relv;
        f16x4 z4 = {0, 0, 0, 0};
        f16x8 z8 = {0, 0, 0, 0, 0, 0, 0, 0};
        *(f16x4*)(xr + 68) = z4;     // zero pad cols 68..95
        *(f16x8*)(xr + 72) = z8;
        *(f16x8*)(xr + 80) = z8;
        *(f16x8*)(xr + 88) = z8;
      }
    }
    __syncthreads();

    mlp_layer<3, K0P>(X, wt0, b0, wv, col, quad);
    mlp_layer<8, D>(X, wt1, b1, wv, col, quad);
    mlp_layer<8, D>(X, wt2, b2, wv, col, quad);
    mlp_layer<8, D>(X, wt3, b3, wv, col, quad);

    // ---- final layer 256 -> 16 (3 real feats); wave handles its 32 queries ----
    // Same 2-deep register pipeline as the hidden layers.
    f32x4 facc[2];
    facc[0] = 0.0f; facc[1] = 0.0f;
    {
      const f16* ap = wt4 + col * D + quad * 8;              // A[m=feat=col][k]
      const f16* bp = X + (wv * 32 + col) * STR + quad * 8;  // B[n=query]
      f16x8 a4[2], bq[2][2];
      a4[0]    = *(const f16x8*)(ap);
      bq[0][0] = *(const f16x8*)(bp);
      bq[0][1] = *(const f16x8*)(bp + 16 * STR);
#pragma unroll
      for (int s = 0; s < 8; ++s) {
        const int cur = s & 1, nxt = cur ^ 1;
        if (s + 1 < 8) {
          a4[nxt]    = *(const f16x8*)(ap + (s + 1) * 32);
          bq[nxt][0] = *(const f16x8*)(bp + (s + 1) * 32);
          bq[nxt][1] = *(const f16x8*)(bp + 16 * STR + (s + 1) * 32);
        }
        __builtin_amdgcn_s_setprio(1);
        facc[0] = MFMA(a4[cur], bq[cur][0], facc[0]);
        facc[1] = MFMA(a4[cur], bq[cur][1], facc[1]);
        __builtin_amdgcn_s_setprio(0);
      }
    }
    // D: row=feat=quad*4+i, col=query. Blend into oacc.
#pragma unroll
    for (int nt = 0; nt < 2; ++nt) {
      int q = q0 + wv * 32 + nt * 16 + col;
      float w = blend_wt(q, t);
#pragma unroll
      for (int i = 0; i < 4; ++i) oacc[nt][i] += (facc[nt][i] + bias4[i]) * w;
    }
  }

  // out[n][c][q]; lanes with quad==0 hold feats 0..3 (3 real) for their queries
  if (quad == 0) {
#pragma unroll
    for (int nt = 0; nt < 2; ++nt) {
      int q = q0 + wv * 32 + nt * 16 + col;
#pragma unroll
      for (int c = 0; c < 3; ++c)
        out[(((size_t)(n * 3 + c)) << 16) + q] = oacc[nt][c];
    }
  }
}

extern "C" void kernel_launch(void* const* d_in, const int* in_sizes, int n_in,
                              void* d_out, int out_size, void* d_ws, size_t ws_size,
                              hipStream_t stream) {
  const float* feat = (const float*)d_in[0];
  const float* w0 = (const float*)d_in[1];
  const float* b0 = (const float*)d_in[2];
  const float* w1 = (const float*)d_in[3];
  const float* b1 = (const float*)d_in[4];
  const float* w2 = (const float*)d_in[5];
  const float* b2 = (const float*)d_in[6];
  const float* w3 = (const float*)d_in[7];
  const float* b3 = (const float*)d_in[8];
  const float* w4 = (const float*)d_in[9];
  const float* b4 = (const float*)d_in[10];

  char* ws = (char*)d_ws;
  f16* featT = (f16*)(ws + OFF_FEAT);
  f16* wt0 = (f16*)(ws + OFF_W0);
  f16* wt1 = (f16*)(ws + OFF_W1);
  f16* wt2 = (f16*)(ws + OFF_W2);
  f16* wt3 = (f16*)(ws + OFF_W3);
  f16* wt4 = (f16*)(ws + OFF_W4);

  prep_feat<<<4096, 256, 0, stream>>>(feat, featT);
  prep_w<<<(256 * 96 + 255) / 256, 256, 0, stream>>>(w0, wt0, 68, 256, 96, 256);
  prep_w<<<256, 256, 0, stream>>>(w1, wt1, 256, 256, 256, 256);
  prep_w<<<256, 256, 0, stream>>>(w2, wt2, 256, 256, 256, 256);
  prep_w<<<256, 256, 0, stream>>>(w3, wt3, 256, 256, 256, 256);
  prep_w<<<(16 * 256 + 255) / 256, 256, 0, stream>>>(w4, wt4, 256, 3, 256, 16);

  liif_main<<<Q * 4 / R, 256, 0, stream>>>(featT, wt0, wt1, wt2, wt3, wt4,
                                           b0, b1, b2, b3, b4, (float*)d_out);
}

// Round 2
// 1227.373 us; speedup vs baseline: 1.1858x; 1.1858x over previous
//
#include <hip/hip_runtime.h>

// LIIF render, fully fused, fp16 MFMA. Round 5: pipelining WITHIN the register
// budget via n-split layers.
// Round-4 post-mortem: FETCH 11.6MB->2.1GB, WRITE 35MB->1.1GB = register
// spill to scratch. At 2 blocks/CU (LDS-bound) the unified budget is 256
// regs/wave; round-3 was already at cap (acc 128 + arch 128). The +96-reg
// double buffers could not fit -> acc spilled every k-step.
// Round-5 changes:
//  - Each hidden layer processes queries in TWO halves of 64 rows (nt 0..3),
//    run sequentially: acc shrinks 128 -> 64 regs, freeing ~64 regs.
//  - Freed registers spent on REAL pipelining: 3-slot ring for A (global
//    weight fragments, ~200cy L2 latency, prefetch distance 2) and 2-slot
//    ring for B (LDS fragments, ~120cy, distance 1). All ring indices are
//    compile-time after full unroll (no scratch from dynamic indexing).
//  - In-place update stays legal: h0's write (rows 0..63) is disjoint from
//    h1's reads (rows 64..127). Layer = [h0 reads] S [h0 write | h1 reads]
//    S [h1 write] -- still 2 barriers/layer; h0 epilogue overlaps h1 loads.
//    One extra sync before the final layer (it reads rows of both halves).
//  - Cost: weight stream read twice per layer (~7.2GB L2 over the dispatch,
//    ~18 TB/s at the target time -- under the 34.5 TB/s L2 ceiling).

typedef _Float16 f16;
typedef _Float16 f16x8 __attribute__((ext_vector_type(8)));
typedef _Float16 f16x4 __attribute__((ext_vector_type(4)));
typedef float    f32x4 __attribute__((ext_vector_type(4)));

#define MFMA(a, b, c) __builtin_amdgcn_mfma_f32_16x16x32_f16((a), (b), (c), 0, 0, 0)

constexpr int HF = 64, WF = 64;         // feature map dims
constexpr int HO = 256, WO = 256;       // output dims
constexpr int Q = HO * WO;              // 65536 queries per image
constexpr int D = 256;                  // hidden width
constexpr int K0P = 96;                 // input dim 68 padded to 96 (3 k-steps)
constexpr int STR = 264;                // LDS row stride (halves)
constexpr int R = 128;                  // query rows per block

// workspace layout (bytes)
constexpr size_t OFF_FEAT = 0;                        // 4*4096*64*2 = 2 MiB
constexpr size_t OFF_W0   = 2097152;                  // 256*96*2
constexpr size_t OFF_W1   = OFF_W0 + 256 * 96 * 2;    // 256*256*2
constexpr size_t OFF_W2   = OFF_W1 + 256 * 256 * 2;
constexpr size_t OFF_W3   = OFF_W2 + 256 * 256 * 2;
constexpr size_t OFF_W4   = OFF_W3 + 256 * 256 * 2;   // 16*256*2

// (N,C,Hf,Wf) fp32 -> (N, Hf*Wf, C) fp16 so a gather row is 128 B contiguous.
__global__ void prep_feat(const float* __restrict__ f, f16* __restrict__ ft) {
  int idx = blockIdx.x * 256 + threadIdx.x;          // 1,048,576 total
  int c = idx & 63, p = (idx >> 6) & 4095, n = idx >> 18;
  ft[idx] = (f16)f[((((size_t)n << 6) | c) << 12) | p];
}

// w (K x N) fp32 -> wt (Npad x Kpad) fp16, zero-padded.
__global__ void prep_w(const float* __restrict__ w, f16* __restrict__ wt,
                       int K, int N, int Kpad, int Npad) {
  int idx = blockIdx.x * 256 + threadIdx.x;
  if (idx >= Npad * Kpad) return;
  int k = idx % Kpad, n = idx / Kpad;
  wt[idx] = (f16)((k < K && n < N) ? w[k * N + n] : 0.0f);
}

// Geometry for query q, tap (vx, vy): feature pixel p and rel coords.
__device__ __forceinline__ void tap_geom(int q, float vx, float vy,
                                         int& p, float& rel0, float& rel1) {
  int qy = q >> 8, qx = q & (WO - 1);
  float cy0 = (float)(2 * qy + 1) * (1.0f / HO) - 1.0f;
  float cx0 = (float)(2 * qx + 1) * (1.0f / WO) - 1.0f;
  float cy = cy0 + vx * (1.0f / HF) + 1e-6f;
  float cx = cx0 + vy * (1.0f / WF) + 1e-6f;
  cy = fminf(fmaxf(cy, -1.0f + 1e-6f), 1.0f - 1e-6f);
  cx = fminf(fmaxf(cx, -1.0f + 1e-6f), 1.0f - 1e-6f);
  int iy = (int)rintf(((cy + 1.0f) * (float)HF - 1.0f) * 0.5f);  // rndne == jnp.round
  int ix = (int)rintf(((cx + 1.0f) * (float)WF - 1.0f) * 0.5f);
  iy = min(max(iy, 0), HF - 1);
  ix = min(max(ix, 0), WF - 1);
  p = (iy << 6) | ix;
  rel0 = (cy0 - ((float)(2 * iy + 1) * (1.0f / HF) - 1.0f)) * (float)HF;
  rel1 = (cx0 - ((float)(2 * ix + 1) * (1.0f / WF) - 1.0f)) * (float)WF;
}

// Blend weight for tap t, query q: preds[t] pairs with areas[3-t].
__device__ __forceinline__ float blend_wt(int q, int t) {
  float a[4], tot = 0.0f;
#pragma unroll
  for (int u = 0; u < 4; ++u) {
    int p; float r0, r1;
    tap_geom(q, (u & 2) ? 1.0f : -1.0f, (u & 1) ? 1.0f : -1.0f, p, r0, r1);
    a[u] = fabsf(r0 * r1) + 1e-9f;
    tot += a[u];
  }
  float sel = (t == 0) ? a[3] : (t == 1) ? a[2] : (t == 2) ? a[1] : a[0];
  return sel / tot;
}

// One HALF (64 query rows, h=0/1) of one hidden layer, pipelined.
// m = out-feature (wave owns feats [wv*64, wv*64+64)), n = query row in half.
// acc 4x4 = 64 regs; A ring 3x4 frags (prefetch dist 2 over ~200cy L2 lat);
// B ring 2x4 frags (dist 1 over ~120cy LDS lat). Ends with the half's write;
// caller supplies the barrier between the k-loop and the write.
template <int KSTEPS, int KPAD>
__device__ __forceinline__ void mlp_half(f16* X, const f16* __restrict__ wt,
                                         const float* __restrict__ bv,
                                         int wv, int col, int quad, int h) {
  f32x4 acc[4][4];
#pragma unroll
  for (int mt = 0; mt < 4; ++mt)
#pragma unroll
    for (int nt = 0; nt < 4; ++nt) acc[mt][nt] = 0.0f;

  const f16* ap = wt + (wv * 64 + col) * KPAD + quad * 8;       // A[m][k]
  const f16* bp = X + (h * 64 + col) * STR + quad * 8;          // B[n][k]

  f16x8 a[3][4], b[2][4];
  // prologue: A for steps 0,1; B for step 0
#pragma unroll
  for (int mt = 0; mt < 4; ++mt)
    a[0][mt] = *(const f16x8*)(ap + mt * 16 * KPAD);
  if (KSTEPS > 1) {
#pragma unroll
    for (int mt = 0; mt < 4; ++mt)
      a[1][mt] = *(const f16x8*)(ap + 32 + mt * 16 * KPAD);
  }
#pragma unroll
  for (int nt = 0; nt < 4; ++nt)
    b[0][nt] = *(const f16x8*)(bp + nt * 16 * STR);

#pragma unroll
  for (int s = 0; s < KSTEPS; ++s) {
    if (s + 2 < KSTEPS) {               // A prefetch, distance 2
#pragma unroll
      for (int mt = 0; mt < 4; ++mt)
        a[(s + 2) % 3][mt] = *(const f16x8*)(ap + (s + 2) * 32 + mt * 16 * KPAD);
    }
    if (s + 1 < KSTEPS) {               // B prefetch, distance 1
#pragma unroll
      for (int nt = 0; nt < 4; ++nt)
        b[(s + 1) & 1][nt] = *(const f16x8*)(bp + (s + 1) * 32 + nt * 16 * STR);
    }
    __builtin_amdgcn_s_setprio(1);
#pragma unroll
    for (int mt = 0; mt < 4; ++mt)
#pragma unroll
      for (int nt = 0; nt < 4; ++nt)
        acc[mt][nt] = MFMA(a[s % 3][mt], b[s & 1][nt], acc[mt][nt]);
    __builtin_amdgcn_s_setprio(0);
  }

  // bias preload before the barrier: L1/L2 latency hides under the wait
  float4 bb[4];
#pragma unroll
  for (int mt = 0; mt < 4; ++mt)
    bb[mt] = *(const float4*)(bv + wv * 64 + mt * 16 + quad * 4);

  __syncthreads();   // all waves' reads of this half's rows complete
  // D: row(m=feat) = mt*16 + quad*4 + i, col(n) = nt*16 + col (within half).
#pragma unroll
  for (int mt = 0; mt < 4; ++mt) {
#pragma unroll
    for (int nt = 0; nt < 4; ++nt) {
      f16x4 y;
      y[0] = (f16)fmaxf(acc[mt][nt][0] + bb[mt].x, 0.0f);
      y[1] = (f16)fmaxf(acc[mt][nt][1] + bb[mt].y, 0.0f);
      y[2] = (f16)fmaxf(acc[mt][nt][2] + bb[mt].z, 0.0f);
      y[3] = (f16)fmaxf(acc[mt][nt][3] + bb[mt].w, 0.0f);
      *(f16x4*)(X + (h * 64 + nt * 16 + col) * STR + wv * 64 + mt * 16 + quad * 4) = y;
    }
  }
}

// Full layer: [h0 k-loop] S [h0 write | h1 k-loop] S [h1 write].
// h0's write (rows 0..63) is disjoint from h1's reads (rows 64..127), so
// no barrier between them; next layer's first sync orders h1's write.
template <int KSTEPS, int KPAD>
__device__ __forceinline__ void mlp_layer(f16* X, const f16* __restrict__ wt,
                                          const float* __restrict__ bv,
                                          int wv, int col, int quad) {
  mlp_half<KSTEPS, KPAD>(X, wt, bv, wv, col, quad, 0);
  mlp_half<KSTEPS, KPAD>(X, wt, bv, wv, col, quad, 1);
}

__global__ __launch_bounds__(256, 2) void liif_main(
    const f16* __restrict__ featT,
    const f16* __restrict__ wt0, const f16* __restrict__ wt1,
    const f16* __restrict__ wt2, const f16* __restrict__ wt3,
    const f16* __restrict__ wt4,
    const float* __restrict__ b0, const float* __restrict__ b1,
    const float* __restrict__ b2, const float* __restrict__ b3,
    const float* __restrict__ b4, float* __restrict__ out) {
  __shared__ __attribute__((aligned(16))) f16 X[R * STR];   // 67.6 KB
  const int tid = threadIdx.x;
  const int wv = tid >> 6;
  const int lane = tid & 63;
  const int row0 = blockIdx.x * R;               // rows = n*Q + q, 128 per block
  const int n = row0 >> 16;
  const int q0 = row0 & (Q - 1);
  const int col = lane & 15, quad = lane >> 4;

  float oacc[2][4] = {{0, 0, 0, 0}, {0, 0, 0, 0}};
  float bias4[4];
#pragma unroll
  for (int i = 0; i < 4; ++i) bias4[i] = (i < 3) ? b4[i] : 0.0f;

#pragma unroll 1
  for (int t = 0; t < 4; ++t) {
    const float vx = (t & 2) ? 1.0f : -1.0f;
    const float vy = (t & 1) ? 1.0f : -1.0f;

    __syncthreads();   // previous tap's reads of X complete
    // ---- gather X0: 64 feat + rel(2) + rel_cell(2), pad to 96 ----
    {
      const int gr = tid >> 1, hf = tid & 1;   // 2 threads per row, 64 B each
      int p; float r0, r1;
      tap_geom(q0 + gr, vx, vy, p, r0, r1);
      const f16x8* src = (const f16x8*)(featT + (((size_t)n << 12) + p) * 64 + hf * 32);
      f16x8* dst = (f16x8*)(X + gr * STR + hf * 32);
      dst[0] = src[0]; dst[1] = src[1]; dst[2] = src[2]; dst[3] = src[3];
      if (tid < R) {
        int p2; float s0, s1;
        tap_geom(q0 + tid, vx, vy, p2, s0, s1);
        f16* xr = X + tid * STR;
        f16x4 relv = {(f16)s0, (f16)s1, (f16)0.5f, (f16)0.5f};
        *(f16x4*)(xr + 64) = relv;
        f16x4 z4 = {0, 0, 0, 0};
        f16x8 z8 = {0, 0, 0, 0, 0, 0, 0, 0};
        *(f16x4*)(xr + 68) = z4;     // zero pad cols 68..95
        *(f16x8*)(xr + 72) = z8;
        *(f16x8*)(xr + 80) = z8;
        *(f16x8*)(xr + 88) = z8;
      }
    }
    __syncthreads();

    mlp_layer<3, K0P>(X, wt0, b0, wv, col, quad);
    mlp_layer<8, D>(X, wt1, b1, wv, col, quad);
    mlp_layer<8, D>(X, wt2, b2, wv, col, quad);
    mlp_layer<8, D>(X, wt3, b3, wv, col, quad);
    __syncthreads();   // final layer reads rows of BOTH halves of layer-3 out

    // ---- final layer 256 -> 16 (3 real feats); wave handles its 32 queries ----
    f32x4 facc[2];
    facc[0] = 0.0f; facc[1] = 0.0f;
    {
      const f16* ap = wt4 + col * D + quad * 8;              // A[m=feat=col][k]
      const f16* bp = X + (wv * 32 + col) * STR + quad * 8;  // B[n=query]
#pragma unroll 1
      for (int s = 0; s < 8; ++s) {
        f16x8 a = *(const f16x8*)(ap + s * 32);
        f16x8 bq0 = *(const f16x8*)(bp + s * 32);
        f16x8 bq1 = *(const f16x8*)(bp + 16 * STR + s * 32);
        facc[0] = MFMA(a, bq0, facc[0]);
        facc[1] = MFMA(a, bq1, facc[1]);
      }
    }
    // D: row=feat=quad*4+i, col=query. Blend into oacc.
#pragma unroll
    for (int nt = 0; nt < 2; ++nt) {
      int q = q0 + wv * 32 + nt * 16 + col;
      float w = blend_wt(q, t);
#pragma unroll
      for (int i = 0; i < 4; ++i) oacc[nt][i] += (facc[nt][i] + bias4[i]) * w;
    }
  }

  // out[n][c][q]; lanes with quad==0 hold feats 0..3 (3 real) for their queries
  if (quad == 0) {
#pragma unroll
    for (int nt = 0; nt < 2; ++nt) {
      int q = q0 + wv * 32 + nt * 16 + col;
#pragma unroll
      for (int c = 0; c < 3; ++c)
        out[(((size_t)(n * 3 + c)) << 16) + q] = oacc[nt][c];
    }
  }
}

extern "C" void kernel_launch(void* const* d_in, const int* in_sizes, int n_in,
                              void* d_out, int out_size, void* d_ws, size_t ws_size,
                              hipStream_t stream) {
  const float* feat = (const float*)d_in[0];
  const float* w0 = (const float*)d_in[1];
  const float* b0 = (const float*)d_in[2];
  const float* w1 = (const float*)d_in[3];
  const float* b1 = (const float*)d_in[4];
  const float* w2 = (const float*)d_in[5];
  const float* b2 = (const float*)d_in[6];
  const float* w3 = (const float*)d_in[7];
  const float* b3 = (const float*)d_in[8];
  const float* w4 = (const float*)d_in[9];
  const float* b4 = (const float*)d_in[10];

  char* ws = (char*)d_ws;
  f16* featT = (f16*)(ws + OFF_FEAT);
  f16* wt0 = (f16*)(ws + OFF_W0);
  f16* wt1 = (f16*)(ws + OFF_W1);
  f16* wt2 = (f16*)(ws + OFF_W2);
  f16* wt3 = (f16*)(ws + OFF_W3);
  f16* wt4 = (f16*)(ws + OFF_W4);

  prep_feat<<<4096, 256, 0, stream>>>(feat, featT);
  prep_w<<<(256 * 96 + 255) / 256, 256, 0, stream>>>(w0, wt0, 68, 256, 96, 256);
  prep_w<<<256, 256, 0, stream>>>(w1, wt1, 256, 256, 256, 256);
  prep_w<<<256, 256, 0, stream>>>(w2, wt2, 256, 256, 256, 256);
  prep_w<<<256, 256, 0, stream>>>(w3, wt3, 256, 256, 256, 256);
  prep_w<<<(16 * 256 + 255) / 256, 256, 0, stream>>>(w4, wt4, 256, 3, 256, 16);

  liif_main<<<Q * 4 / R, 256, 0, stream>>>(featT, wt0, wt1, wt2, wt3, wt4,
                                           b0, b1, b2, b3, b4, (float*)d_out);
}

// Round 3
// 909.070 us; speedup vs baseline: 1.6010x; 1.3501x over previous
//
#include <hip/hip_runtime.h>

// LIIF render, fully fused, fp16 MFMA. Round 6: pipelining with a ROLLED loop.
// Round-4/5 post-mortem: identical 2.1GB/1.1GB scratch traffic in both rounds
// despite very different register demand -> the spill cause was the FULL
// UNROLL of the k-loop (needed for s%3 ring indices), which let the scheduler
// float all steps' loads upward and blow past the 256-reg unified budget.
// Round 3 (606us, no spill) had "#pragma unroll 1". The pipelining idea was
// never actually tested.
// Round-6 changes:
//  - Keep round-5's n-half split (acc[4][4]=64 regs, verified barrier scheme).
//  - k-loop is "#pragma unroll 1" over PAIRS of k-steps with NAMED ping-pong
//    buffers (aA/bA, aB/bB): prefetch s+1 into B -> MFMA burst A -> prefetch
//    s+2 into A -> MFMA burst B. Loads sit a full ~310cy MFMA burst ahead of
//    their use; loop body stays compact so pressure peaks ~200 regs.
//  - No numerics change: same per-output k-accumulation order as rounds 3/5
//    (absmax is exactly at threshold; numerics are frozen).
// Validation gates: FETCH ~12MB / WRITE ~36MB (spill gone), then MfmaUtil.

typedef _Float16 f16;
typedef _Float16 f16x8 __attribute__((ext_vector_type(8)));
typedef _Float16 f16x4 __attribute__((ext_vector_type(4)));
typedef float    f32x4 __attribute__((ext_vector_type(4)));

#define MFMA(a, b, c) __builtin_amdgcn_mfma_f32_16x16x32_f16((a), (b), (c), 0, 0, 0)

constexpr int HF = 64, WF = 64;         // feature map dims
constexpr int HO = 256, WO = 256;       // output dims
constexpr int Q = HO * WO;              // 65536 queries per image
constexpr int D = 256;                  // hidden width
constexpr int K0P = 96;                 // input dim 68 padded to 96 (3 k-steps)
constexpr int STR = 264;                // LDS row stride (halves)
constexpr int R = 128;                  // query rows per block

// workspace layout (bytes)
constexpr size_t OFF_FEAT = 0;                        // 4*4096*64*2 = 2 MiB
constexpr size_t OFF_W0   = 2097152;                  // 256*96*2
constexpr size_t OFF_W1   = OFF_W0 + 256 * 96 * 2;    // 256*256*2
constexpr size_t OFF_W2   = OFF_W1 + 256 * 256 * 2;
constexpr size_t OFF_W3   = OFF_W2 + 256 * 256 * 2;
constexpr size_t OFF_W4   = OFF_W3 + 256 * 256 * 2;   // 16*256*2

// (N,C,Hf,Wf) fp32 -> (N, Hf*Wf, C) fp16 so a gather row is 128 B contiguous.
__global__ void prep_feat(const float* __restrict__ f, f16* __restrict__ ft) {
  int idx = blockIdx.x * 256 + threadIdx.x;          // 1,048,576 total
  int c = idx & 63, p = (idx >> 6) & 4095, n = idx >> 18;
  ft[idx] = (f16)f[((((size_t)n << 6) | c) << 12) | p];
}

// w (K x N) fp32 -> wt (Npad x Kpad) fp16, zero-padded.
__global__ void prep_w(const float* __restrict__ w, f16* __restrict__ wt,
                       int K, int N, int Kpad, int Npad) {
  int idx = blockIdx.x * 256 + threadIdx.x;
  if (idx >= Npad * Kpad) return;
  int k = idx % Kpad, n = idx / Kpad;
  wt[idx] = (f16)((k < K && n < N) ? w[k * N + n] : 0.0f);
}

// Geometry for query q, tap (vx, vy): feature pixel p and rel coords.
__device__ __forceinline__ void tap_geom(int q, float vx, float vy,
                                         int& p, float& rel0, float& rel1) {
  int qy = q >> 8, qx = q & (WO - 1);
  float cy0 = (float)(2 * qy + 1) * (1.0f / HO) - 1.0f;
  float cx0 = (float)(2 * qx + 1) * (1.0f / WO) - 1.0f;
  float cy = cy0 + vx * (1.0f / HF) + 1e-6f;
  float cx = cx0 + vy * (1.0f / WF) + 1e-6f;
  cy = fminf(fmaxf(cy, -1.0f + 1e-6f), 1.0f - 1e-6f);
  cx = fminf(fmaxf(cx, -1.0f + 1e-6f), 1.0f - 1e-6f);
  int iy = (int)rintf(((cy + 1.0f) * (float)HF - 1.0f) * 0.5f);  // rndne == jnp.round
  int ix = (int)rintf(((cx + 1.0f) * (float)WF - 1.0f) * 0.5f);
  iy = min(max(iy, 0), HF - 1);
  ix = min(max(ix, 0), WF - 1);
  p = (iy << 6) | ix;
  rel0 = (cy0 - ((float)(2 * iy + 1) * (1.0f / HF) - 1.0f)) * (float)HF;
  rel1 = (cx0 - ((float)(2 * ix + 1) * (1.0f / WF) - 1.0f)) * (float)WF;
}

// Blend weight for tap t, query q: preds[t] pairs with areas[3-t].
__device__ __forceinline__ float blend_wt(int q, int t) {
  float a[4], tot = 0.0f;
#pragma unroll
  for (int u = 0; u < 4; ++u) {
    int p; float r0, r1;
    tap_geom(q, (u & 2) ? 1.0f : -1.0f, (u & 1) ? 1.0f : -1.0f, p, r0, r1);
    a[u] = fabsf(r0 * r1) + 1e-9f;
    tot += a[u];
  }
  float sel = (t == 0) ? a[3] : (t == 1) ? a[2] : (t == 2) ? a[1] : a[0];
  return sel / tot;
}

// One HALF (64 query rows, h=0/1) of one hidden layer, software-pipelined.
// m = out-feature (wave owns feats [wv*64, wv*64+64)), n = query row in half.
// acc 4x4 = 64 regs. Rolled (#pragma unroll 1) loop over PAIRS of k-steps
// with named ping-pong operand buffers: prefetch of step s+1 issues before
// the MFMA burst of step s. Peak pressure ~200 regs (no spill at the
// 256-reg/wave cap imposed by launch_bounds(256,2)).
template <int KSTEPS, int KPAD>
__device__ __forceinline__ void mlp_half(f16* X, const f16* __restrict__ wt,
                                         const float* __restrict__ bv,
                                         int wv, int col, int quad, int h) {
  f32x4 acc[4][4];
#pragma unroll
  for (int mt = 0; mt < 4; ++mt)
#pragma unroll
    for (int nt = 0; nt < 4; ++nt) acc[mt][nt] = 0.0f;

  const f16* ap = wt + (wv * 64 + col) * KPAD + quad * 8;       // A[m][k]
  const f16* bp = X + (h * 64 + col) * STR + quad * 8;          // B[n][k]

  f16x8 aA[4], aB[4], bA[4], bB[4];
#pragma unroll
  for (int mt = 0; mt < 4; ++mt)
    aA[mt] = *(const f16x8*)(ap + mt * 16 * KPAD);
#pragma unroll
  for (int nt = 0; nt < 4; ++nt)
    bA[nt] = *(const f16x8*)(bp + nt * 16 * STR);

#pragma unroll 1
  for (int s = 0; s + 1 < KSTEPS; s += 2) {
    // prefetch step s+1 into the B buffers (hides under burst A)
#pragma unroll
    for (int mt = 0; mt < 4; ++mt)
      aB[mt] = *(const f16x8*)(ap + (s + 1) * 32 + mt * 16 * KPAD);
#pragma unroll
    for (int nt = 0; nt < 4; ++nt)
      bB[nt] = *(const f16x8*)(bp + (s + 1) * 32 + nt * 16 * STR);
    __builtin_amdgcn_s_setprio(1);
#pragma unroll
    for (int mt = 0; mt < 4; ++mt)
#pragma unroll
      for (int nt = 0; nt < 4; ++nt)
        acc[mt][nt] = MFMA(aA[mt], bA[nt], acc[mt][nt]);
    __builtin_amdgcn_s_setprio(0);
    if (s + 2 < KSTEPS) {     // prefetch step s+2 into A (hides under burst B)
#pragma unroll
      for (int mt = 0; mt < 4; ++mt)
        aA[mt] = *(const f16x8*)(ap + (s + 2) * 32 + mt * 16 * KPAD);
#pragma unroll
      for (int nt = 0; nt < 4; ++nt)
        bA[nt] = *(const f16x8*)(bp + (s + 2) * 32 + nt * 16 * STR);
    }
    __builtin_amdgcn_s_setprio(1);
#pragma unroll
    for (int mt = 0; mt < 4; ++mt)
#pragma unroll
      for (int nt = 0; nt < 4; ++nt)
        acc[mt][nt] = MFMA(aB[mt], bB[nt], acc[mt][nt]);
    __builtin_amdgcn_s_setprio(0);
  }
  if constexpr (KSTEPS & 1) {   // final odd step sits in the A buffers
    __builtin_amdgcn_s_setprio(1);
#pragma unroll
    for (int mt = 0; mt < 4; ++mt)
#pragma unroll
      for (int nt = 0; nt < 4; ++nt)
        acc[mt][nt] = MFMA(aA[mt], bA[nt], acc[mt][nt]);
    __builtin_amdgcn_s_setprio(0);
  }

  // bias preload before the barrier: L1/L2 latency hides under the wait
  float4 bb[4];
#pragma unroll
  for (int mt = 0; mt < 4; ++mt)
    bb[mt] = *(const float4*)(bv + wv * 64 + mt * 16 + quad * 4);

  __syncthreads();   // all waves' reads of this half's rows complete
  // D: row(m=feat) = mt*16 + quad*4 + i, col(n) = nt*16 + col (within half).
#pragma unroll
  for (int mt = 0; mt < 4; ++mt) {
#pragma unroll
    for (int nt = 0; nt < 4; ++nt) {
      f16x4 y;
      y[0] = (f16)fmaxf(acc[mt][nt][0] + bb[mt].x, 0.0f);
      y[1] = (f16)fmaxf(acc[mt][nt][1] + bb[mt].y, 0.0f);
      y[2] = (f16)fmaxf(acc[mt][nt][2] + bb[mt].z, 0.0f);
      y[3] = (f16)fmaxf(acc[mt][nt][3] + bb[mt].w, 0.0f);
      *(f16x4*)(X + (h * 64 + nt * 16 + col) * STR + wv * 64 + mt * 16 + quad * 4) = y;
    }
  }
}

// Full layer: [h0 k-loop] S [h0 write | h1 k-loop] S [h1 write].
// h0's write (rows 0..63) is disjoint from h1's reads (rows 64..127), so
// no barrier between them; next layer's first sync orders h1's write.
template <int KSTEPS, int KPAD>
__device__ __forceinline__ void mlp_layer(f16* X, const f16* __restrict__ wt,
                                          const float* __restrict__ bv,
                                          int wv, int col, int quad) {
  mlp_half<KSTEPS, KPAD>(X, wt, bv, wv, col, quad, 0);
  mlp_half<KSTEPS, KPAD>(X, wt, bv, wv, col, quad, 1);
}

__global__ __launch_bounds__(256, 2) void liif_main(
    const f16* __restrict__ featT,
    const f16* __restrict__ wt0, const f16* __restrict__ wt1,
    const f16* __restrict__ wt2, const f16* __restrict__ wt3,
    const f16* __restrict__ wt4,
    const float* __restrict__ b0, const float* __restrict__ b1,
    const float* __restrict__ b2, const float* __restrict__ b3,
    const float* __restrict__ b4, float* __restrict__ out) {
  __shared__ __attribute__((aligned(16))) f16 X[R * STR];   // 67.6 KB
  const int tid = threadIdx.x;
  const int wv = tid >> 6;
  const int lane = tid & 63;
  const int row0 = blockIdx.x * R;               // rows = n*Q + q, 128 per block
  const int n = row0 >> 16;
  const int q0 = row0 & (Q - 1);
  const int col = lane & 15, quad = lane >> 4;

  float oacc[2][4] = {{0, 0, 0, 0}, {0, 0, 0, 0}};
  float bias4[4];
#pragma unroll
  for (int i = 0; i < 4; ++i) bias4[i] = (i < 3) ? b4[i] : 0.0f;

#pragma unroll 1
  for (int t = 0; t < 4; ++t) {
    const float vx = (t & 2) ? 1.0f : -1.0f;
    const float vy = (t & 1) ? 1.0f : -1.0f;

    __syncthreads();   // previous tap's reads of X complete
    // ---- gather X0: 64 feat + rel(2) + rel_cell(2), pad to 96 ----
    {
      const int gr = tid >> 1, hf = tid & 1;   // 2 threads per row, 64 B each
      int p; float r0, r1;
      tap_geom(q0 + gr, vx, vy, p, r0, r1);
      const f16x8* src = (const f16x8*)(featT + (((size_t)n << 12) + p) * 64 + hf * 32);
      f16x8* dst = (f16x8*)(X + gr * STR + hf * 32);
      dst[0] = src[0]; dst[1] = src[1]; dst[2] = src[2]; dst[3] = src[3];
      if (tid < R) {
        int p2; float s0, s1;
        tap_geom(q0 + tid, vx, vy, p2, s0, s1);
        f16* xr = X + tid * STR;
        f16x4 relv = {(f16)s0, (f16)s1, (f16)0.5f, (f16)0.5f};
        *(f16x4*)(xr + 64) = relv;
        f16x4 z4 = {0, 0, 0, 0};
        f16x8 z8 = {0, 0, 0, 0, 0, 0, 0, 0};
        *(f16x4*)(xr + 68) = z4;     // zero pad cols 68..95
        *(f16x8*)(xr + 72) = z8;
        *(f16x8*)(xr + 80) = z8;
        *(f16x8*)(xr + 88) = z8;
      }
    }
    __syncthreads();

    mlp_layer<3, K0P>(X, wt0, b0, wv, col, quad);
    mlp_layer<8, D>(X, wt1, b1, wv, col, quad);
    mlp_layer<8, D>(X, wt2, b2, wv, col, quad);
    mlp_layer<8, D>(X, wt3, b3, wv, col, quad);
    __syncthreads();   // final layer reads rows of BOTH halves of layer-3 out

    // ---- final layer 256 -> 16 (3 real feats); wave handles its 32 queries ----
    f32x4 facc[2];
    facc[0] = 0.0f; facc[1] = 0.0f;
    {
      const f16* ap = wt4 + col * D + quad * 8;              // A[m=feat=col][k]
      const f16* bp = X + (wv * 32 + col) * STR + quad * 8;  // B[n=query]
#pragma unroll 1
      for (int s = 0; s < 8; ++s) {
        f16x8 a = *(const f16x8*)(ap + s * 32);
        f16x8 bq0 = *(const f16x8*)(bp + s * 32);
        f16x8 bq1 = *(const f16x8*)(bp + 16 * STR + s * 32);
        facc[0] = MFMA(a, bq0, facc[0]);
        facc[1] = MFMA(a, bq1, facc[1]);
      }
    }
    // D: row=feat=quad*4+i, col=query. Blend into oacc.
#pragma unroll
    for (int nt = 0; nt < 2; ++nt) {
      int q = q0 + wv * 32 + nt * 16 + col;
      float w = blend_wt(q, t);
#pragma unroll
      for (int i = 0; i < 4; ++i) oacc[nt][i] += (facc[nt][i] + bias4[i]) * w;
    }
  }

  // out[n][c][q]; lanes with quad==0 hold feats 0..3 (3 real) for their queries
  if (quad == 0) {
#pragma unroll
    for (int nt = 0; nt < 2; ++nt) {
      int q = q0 + wv * 32 + nt * 16 + col;
#pragma unroll
      for (int c = 0; c < 3; ++c)
        out[(((size_t)(n * 3 + c)) << 16) + q] = oacc[nt][c];
    }
  }
}

extern "C" void kernel_launch(void* const* d_in, const int* in_sizes, int n_in,
                              void* d_out, int out_size, void* d_ws, size_t ws_size,
                              hipStream_t stream) {
  const float* feat = (const float*)d_in[0];
  const float* w0 = (const float*)d_in[1];
  const float* b0 = (const float*)d_in[2];
  const float* w1 = (const float*)d_in[3];
  const float* b1 = (const float*)d_in[4];
  const float* w2 = (const float*)d_in[5];
  const float* b2 = (const float*)d_in[6];
  const float* w3 = (const float*)d_in[7];
  const float* b3 = (const float*)d_in[8];
  const float* w4 = (const float*)d_in[9];
  const float* b4 = (const float*)d_in[10];

  char* ws = (char*)d_ws;
  f16* featT = (f16*)(ws + OFF_FEAT);
  f16* wt0 = (f16*)(ws + OFF_W0);
  f16* wt1 = (f16*)(ws + OFF_W1);
  f16* wt2 = (f16*)(ws + OFF_W2);
  f16* wt3 = (f16*)(ws + OFF_W3);
  f16* wt4 = (f16*)(ws + OFF_W4);

  prep_feat<<<4096, 256, 0, stream>>>(feat, featT);
  prep_w<<<(256 * 96 + 255) / 256, 256, 0, stream>>>(w0, wt0, 68, 256, 96, 256);
  prep_w<<<256, 256, 0, stream>>>(w1, wt1, 256, 256, 256, 256);
  prep_w<<<256, 256, 0, stream>>>(w2, wt2, 256, 256, 256, 256);
  prep_w<<<256, 256, 0, stream>>>(w3, wt3, 256, 256, 256, 256);
  prep_w<<<(16 * 256 + 255) / 256, 256, 0, stream>>>(w4, wt4, 256, 3, 256, 16);

  liif_main<<<Q * 4 / R, 256, 0, stream>>>(featT, wt0, wt1, wt2, wt3, wt4,
                                           b0, b1, b2, b3, b4, (float*)d_out);
}

// Round 4
// 895.381 us; speedup vs baseline: 1.6255x; 1.0153x over previous
//
#include <hip/hip_runtime.h>

// LIIF render, fully fused, fp16 MFMA. Round 7: A-only ping-pong within the
// 128-arch-VGPR envelope.
// Cross-round register model (VGPR_Count==128 in ALL rounds, spill scaling
// with operand-buffer count): compiler splits the 256-reg unified budget as
// 128 arch VGPR + 128 AGPR; only MFMA accumulators go to AGPR. Arch side
// must hold operand buffers + addressing + epilogue + outer state:
//   R3: 48 operand + ~50 misc -> fit (no spill, 606us)
//   R6: 64 operand + 16 bias-hoist + ~50 -> ~130 > 128 -> modest spill (909us)
// Round-7 changes vs R6:
//  - Ping-pong ONLY the A (weight) stream: aP/aQ named buffers, prefetch
//    A(s+1) before burst(s). A is the expensive stream: each wave's 32KB
//    W-slice thrashes the 32KB L1 across 8 resident waves -> ~200-400cy L2
//    latency per k-step, previously exposed. B (LDS, ~120cy) stays
//    single-buffered, reloaded between bursts (partially covered by the
//    interleaved A-prefetch issue).
//  - Operand footprint back to R3's 48 regs (aP16+aQ16+b16). Bias load moved
//    AFTER the barrier (no pre-barrier live range). acc=64 leaves 64 spare
//    AGPRs as memory-free spill headroom.
//  - Keeps R6's verified n-half split + barrier scheme and exact numerics.
// Gates: FETCH ~12-15MB / WRITE ~36MB (spill gone), MfmaUtil 45+%, <606us.

typedef _Float16 f16;
typedef _Float16 f16x8 __attribute__((ext_vector_type(8)));
typedef _Float16 f16x4 __attribute__((ext_vector_type(4)));
typedef float    f32x4 __attribute__((ext_vector_type(4)));

#define MFMA(a, b, c) __builtin_amdgcn_mfma_f32_16x16x32_f16((a), (b), (c), 0, 0, 0)

constexpr int HF = 64, WF = 64;         // feature map dims
constexpr int HO = 256, WO = 256;       // output dims
constexpr int Q = HO * WO;              // 65536 queries per image
constexpr int D = 256;                  // hidden width
constexpr int K0P = 96;                 // input dim 68 padded to 96 (3 k-steps)
constexpr int STR = 264;                // LDS row stride (halves)
constexpr int R = 128;                  // query rows per block

// workspace layout (bytes)
constexpr size_t OFF_FEAT = 0;                        // 4*4096*64*2 = 2 MiB
constexpr size_t OFF_W0   = 2097152;                  // 256*96*2
constexpr size_t OFF_W1   = OFF_W0 + 256 * 96 * 2;    // 256*256*2
constexpr size_t OFF_W2   = OFF_W1 + 256 * 256 * 2;
constexpr size_t OFF_W3   = OFF_W2 + 256 * 256 * 2;
constexpr size_t OFF_W4   = OFF_W3 + 256 * 256 * 2;   // 16*256*2

// (N,C,Hf,Wf) fp32 -> (N, Hf*Wf, C) fp16 so a gather row is 128 B contiguous.
__global__ void prep_feat(const float* __restrict__ f, f16* __restrict__ ft) {
  int idx = blockIdx.x * 256 + threadIdx.x;          // 1,048,576 total
  int c = idx & 63, p = (idx >> 6) & 4095, n = idx >> 18;
  ft[idx] = (f16)f[((((size_t)n << 6) | c) << 12) | p];
}

// w (K x N) fp32 -> wt (Npad x Kpad) fp16, zero-padded.
__global__ void prep_w(const float* __restrict__ w, f16* __restrict__ wt,
                       int K, int N, int Kpad, int Npad) {
  int idx = blockIdx.x * 256 + threadIdx.x;
  if (idx >= Npad * Kpad) return;
  int k = idx % Kpad, n = idx / Kpad;
  wt[idx] = (f16)((k < K && n < N) ? w[k * N + n] : 0.0f);
}

// Geometry for query q, tap (vx, vy): feature pixel p and rel coords.
__device__ __forceinline__ void tap_geom(int q, float vx, float vy,
                                         int& p, float& rel0, float& rel1) {
  int qy = q >> 8, qx = q & (WO - 1);
  float cy0 = (float)(2 * qy + 1) * (1.0f / HO) - 1.0f;
  float cx0 = (float)(2 * qx + 1) * (1.0f / WO) - 1.0f;
  float cy = cy0 + vx * (1.0f / HF) + 1e-6f;
  float cx = cx0 + vy * (1.0f / WF) + 1e-6f;
  cy = fminf(fmaxf(cy, -1.0f + 1e-6f), 1.0f - 1e-6f);
  cx = fminf(fmaxf(cx, -1.0f + 1e-6f), 1.0f - 1e-6f);
  int iy = (int)rintf(((cy + 1.0f) * (float)HF - 1.0f) * 0.5f);  // rndne == jnp.round
  int ix = (int)rintf(((cx + 1.0f) * (float)WF - 1.0f) * 0.5f);
  iy = min(max(iy, 0), HF - 1);
  ix = min(max(ix, 0), WF - 1);
  p = (iy << 6) | ix;
  rel0 = (cy0 - ((float)(2 * iy + 1) * (1.0f / HF) - 1.0f)) * (float)HF;
  rel1 = (cx0 - ((float)(2 * ix + 1) * (1.0f / WF) - 1.0f)) * (float)WF;
}

// Blend weight for tap t, query q: preds[t] pairs with areas[3-t].
__device__ __forceinline__ float blend_wt(int q, int t) {
  float a[4], tot = 0.0f;
#pragma unroll
  for (int u = 0; u < 4; ++u) {
    int p; float r0, r1;
    tap_geom(q, (u & 2) ? 1.0f : -1.0f, (u & 1) ? 1.0f : -1.0f, p, r0, r1);
    a[u] = fabsf(r0 * r1) + 1e-9f;
    tot += a[u];
  }
  float sel = (t == 0) ? a[3] : (t == 1) ? a[2] : (t == 2) ? a[1] : a[0];
  return sel / tot;
}

// One HALF (64 query rows, h=0/1) of one hidden layer.
// m = out-feature (wave owns feats [wv*64, wv*64+64)), n = query row in half.
// acc 4x4 = 64 AGPRs. Rolled (#pragma unroll 1) loop over PAIRS of k-steps.
// A (global weights) ping-pongs aP/aQ: A(s+1) prefetch issues before burst(s),
// covering the ~200-400cy L2 latency under ~160cy of MFMA + B-load issue.
// B (LDS) single-buffered: reloaded between bursts (WAR-cleared).
// Arch-operand footprint: 48 regs, same as the proven no-spill round 3.
template <int KSTEPS, int KPAD>
__device__ __forceinline__ void mlp_half(f16* X, const f16* __restrict__ wt,
                                         const float* __restrict__ bv,
                                         int wv, int col, int quad, int h) {
  f32x4 acc[4][4];
#pragma unroll
  for (int mt = 0; mt < 4; ++mt)
#pragma unroll
    for (int nt = 0; nt < 4; ++nt) acc[mt][nt] = 0.0f;

  const f16* ap = wt + (wv * 64 + col) * KPAD + quad * 8;       // A[m][k]
  const f16* bp = X + (h * 64 + col) * STR + quad * 8;          // B[n][k]

  f16x8 aP[4], aQ[4], b[4];
#pragma unroll
  for (int mt = 0; mt < 4; ++mt)
    aP[mt] = *(const f16x8*)(ap + mt * 16 * KPAD);
#pragma unroll
  for (int nt = 0; nt < 4; ++nt)
    b[nt] = *(const f16x8*)(bp + nt * 16 * STR);

#pragma unroll 1
  for (int s = 0; s + 1 < KSTEPS; s += 2) {
    // A(s+1) prefetch into aQ: in flight across burst(s)
#pragma unroll
    for (int mt = 0; mt < 4; ++mt)
      aQ[mt] = *(const f16x8*)(ap + (s + 1) * 32 + mt * 16 * KPAD);
    __builtin_amdgcn_s_setprio(1);
#pragma unroll
    for (int mt = 0; mt < 4; ++mt)
#pragma unroll
      for (int nt = 0; nt < 4; ++nt)
        acc[mt][nt] = MFMA(aP[mt], b[nt], acc[mt][nt]);
    __builtin_amdgcn_s_setprio(0);
    // B(s+1) reload (WAR on b cleared by burst above)
#pragma unroll
    for (int nt = 0; nt < 4; ++nt)
      b[nt] = *(const f16x8*)(bp + (s + 1) * 32 + nt * 16 * STR);
    if (s + 2 < KSTEPS) {     // A(s+2) prefetch into aP: in flight across burst(s+1)
#pragma unroll
      for (int mt = 0; mt < 4; ++mt)
        aP[mt] = *(const f16x8*)(ap + (s + 2) * 32 + mt * 16 * KPAD);
    }
    __builtin_amdgcn_s_setprio(1);
#pragma unroll
    for (int mt = 0; mt < 4; ++mt)
#pragma unroll
      for (int nt = 0; nt < 4; ++nt)
        acc[mt][nt] = MFMA(aQ[mt], b[nt], acc[mt][nt]);
    __builtin_amdgcn_s_setprio(0);
    if (s + 2 < KSTEPS) {     // B(s+2) for the next pair's first burst (or odd tail)
#pragma unroll
      for (int nt = 0; nt < 4; ++nt)
        b[nt] = *(const f16x8*)(bp + (s + 2) * 32 + nt * 16 * STR);
    }
  }
  if constexpr (KSTEPS & 1) {   // final odd step sits in aP / b
    __builtin_amdgcn_s_setprio(1);
#pragma unroll
    for (int mt = 0; mt < 4; ++mt)
#pragma unroll
      for (int nt = 0; nt < 4; ++nt)
        acc[mt][nt] = MFMA(aP[mt], b[nt], acc[mt][nt]);
    __builtin_amdgcn_s_setprio(0);
  }

  __syncthreads();   // all waves' reads of this half's rows complete
  // bias loaded after the barrier: no live range across the k-loop/barrier
  float4 bb[4];
#pragma unroll
  for (int mt = 0; mt < 4; ++mt)
    bb[mt] = *(const float4*)(bv + wv * 64 + mt * 16 + quad * 4);
  // D: row(m=feat) = mt*16 + quad*4 + i, col(n) = nt*16 + col (within half).
#pragma unroll
  for (int mt = 0; mt < 4; ++mt) {
#pragma unroll
    for (int nt = 0; nt < 4; ++nt) {
      f16x4 y;
      y[0] = (f16)fmaxf(acc[mt][nt][0] + bb[mt].x, 0.0f);
      y[1] = (f16)fmaxf(acc[mt][nt][1] + bb[mt].y, 0.0f);
      y[2] = (f16)fmaxf(acc[mt][nt][2] + bb[mt].z, 0.0f);
      y[3] = (f16)fmaxf(acc[mt][nt][3] + bb[mt].w, 0.0f);
      *(f16x4*)(X + (h * 64 + nt * 16 + col) * STR + wv * 64 + mt * 16 + quad * 4) = y;
    }
  }
}

// Full layer: [h0 k-loop] S [h0 write | h1 k-loop] S [h1 write].
// h0's write (rows 0..63) is disjoint from h1's reads (rows 64..127), so
// no barrier between them; next layer's first sync orders h1's write.
template <int KSTEPS, int KPAD>
__device__ __forceinline__ void mlp_layer(f16* X, const f16* __restrict__ wt,
                                          const float* __restrict__ bv,
                                          int wv, int col, int quad) {
  mlp_half<KSTEPS, KPAD>(X, wt, bv, wv, col, quad, 0);
  mlp_half<KSTEPS, KPAD>(X, wt, bv, wv, col, quad, 1);
}

__global__ __launch_bounds__(256, 2) void liif_main(
    const f16* __restrict__ featT,
    const f16* __restrict__ wt0, const f16* __restrict__ wt1,
    const f16* __restrict__ wt2, const f16* __restrict__ wt3,
    const f16* __restrict__ wt4,
    const float* __restrict__ b0, const float* __restrict__ b1,
    const float* __restrict__ b2, const float* __restrict__ b3,
    const float* __restrict__ b4, float* __restrict__ out) {
  __shared__ __attribute__((aligned(16))) f16 X[R * STR];   // 67.6 KB
  const int tid = threadIdx.x;
  const int wv = tid >> 6;
  const int lane = tid & 63;
  const int row0 = blockIdx.x * R;               // rows = n*Q + q, 128 per block
  const int n = row0 >> 16;
  const int q0 = row0 & (Q - 1);
  const int col = lane & 15, quad = lane >> 4;

  float oacc[2][4] = {{0, 0, 0, 0}, {0, 0, 0, 0}};
  float bias4[4];
#pragma unroll
  for (int i = 0; i < 4; ++i) bias4[i] = (i < 3) ? b4[i] : 0.0f;

#pragma unroll 1
  for (int t = 0; t < 4; ++t) {
    const float vx = (t & 2) ? 1.0f : -1.0f;
    const float vy = (t & 1) ? 1.0f : -1.0f;

    __syncthreads();   // previous tap's reads of X complete
    // ---- gather X0: 64 feat + rel(2) + rel_cell(2), pad to 96 ----
    {
      const int gr = tid >> 1, hf = tid & 1;   // 2 threads per row, 64 B each
      int p; float r0, r1;
      tap_geom(q0 + gr, vx, vy, p, r0, r1);
      const f16x8* src = (const f16x8*)(featT + (((size_t)n << 12) + p) * 64 + hf * 32);
      f16x8* dst = (f16x8*)(X + gr * STR + hf * 32);
      dst[0] = src[0]; dst[1] = src[1]; dst[2] = src[2]; dst[3] = src[3];
      if (tid < R) {
        int p2; float s0, s1;
        tap_geom(q0 + tid, vx, vy, p2, s0, s1);
        f16* xr = X + tid * STR;
        f16x4 relv = {(f16)s0, (f16)s1, (f16)0.5f, (f16)0.5f};
        *(f16x4*)(xr + 64) = relv;
        f16x4 z4 = {0, 0, 0, 0};
        f16x8 z8 = {0, 0, 0, 0, 0, 0, 0, 0};
        *(f16x4*)(xr + 68) = z4;     // zero pad cols 68..95
        *(f16x8*)(xr + 72) = z8;
        *(f16x8*)(xr + 80) = z8;
        *(f16x8*)(xr + 88) = z8;
      }
    }
    __syncthreads();

    mlp_layer<3, K0P>(X, wt0, b0, wv, col, quad);
    mlp_layer<8, D>(X, wt1, b1, wv, col, quad);
    mlp_layer<8, D>(X, wt2, b2, wv, col, quad);
    mlp_layer<8, D>(X, wt3, b3, wv, col, quad);
    __syncthreads();   // final layer reads rows of BOTH halves of layer-3 out

    // ---- final layer 256 -> 16 (3 real feats); wave handles its 32 queries ----
    f32x4 facc[2];
    facc[0] = 0.0f; facc[1] = 0.0f;
    {
      const f16* ap = wt4 + col * D + quad * 8;              // A[m=feat=col][k]
      const f16* bp = X + (wv * 32 + col) * STR + quad * 8;  // B[n=query]
#pragma unroll 1
      for (int s = 0; s < 8; ++s) {
        f16x8 a = *(const f16x8*)(ap + s * 32);
        f16x8 bq0 = *(const f16x8*)(bp + s * 32);
        f16x8 bq1 = *(const f16x8*)(bp + 16 * STR + s * 32);
        facc[0] = MFMA(a, bq0, facc[0]);
        facc[1] = MFMA(a, bq1, facc[1]);
      }
    }
    // D: row=feat=quad*4+i, col=query. Blend into oacc.
#pragma unroll
    for (int nt = 0; nt < 2; ++nt) {
      int q = q0 + wv * 32 + nt * 16 + col;
      float w = blend_wt(q, t);
#pragma unroll
      for (int i = 0; i < 4; ++i) oacc[nt][i] += (facc[nt][i] + bias4[i]) * w;
    }
  }

  // out[n][c][q]; lanes with quad==0 hold feats 0..3 (3 real) for their queries
  if (quad == 0) {
#pragma unroll
    for (int nt = 0; nt < 2; ++nt) {
      int q = q0 + wv * 32 + nt * 16 + col;
#pragma unroll
      for (int c = 0; c < 3; ++c)
        out[(((size_t)(n * 3 + c)) << 16) + q] = oacc[nt][c];
    }
  }
}

extern "C" void kernel_launch(void* const* d_in, const int* in_sizes, int n_in,
                              void* d_out, int out_size, void* d_ws, size_t ws_size,
                              hipStream_t stream) {
  const float* feat = (const float*)d_in[0];
  const float* w0 = (const float*)d_in[1];
  const float* b0 = (const float*)d_in[2];
  const float* w1 = (const float*)d_in[3];
  const float* b1 = (const float*)d_in[4];
  const float* w2 = (const float*)d_in[5];
  const float* b2 = (const float*)d_in[6];
  const float* w3 = (const float*)d_in[7];
  const float* b3 = (const float*)d_in[8];
  const float* w4 = (const float*)d_in[9];
  const float* b4 = (const float*)d_in[10];

  char* ws = (char*)d_ws;
  f16* featT = (f16*)(ws + OFF_FEAT);
  f16* wt0 = (f16*)(ws + OFF_W0);
  f16* wt1 = (f16*)(ws + OFF_W1);
  f16* wt2 = (f16*)(ws + OFF_W2);
  f16* wt3 = (f16*)(ws + OFF_W3);
  f16* wt4 = (f16*)(ws + OFF_W4);

  prep_feat<<<4096, 256, 0, stream>>>(feat, featT);
  prep_w<<<(256 * 96 + 255) / 256, 256, 0, stream>>>(w0, wt0, 68, 256, 96, 256);
  prep_w<<<256, 256, 0, stream>>>(w1, wt1, 256, 256, 256, 256);
  prep_w<<<256, 256, 0, stream>>>(w2, wt2, 256, 256, 256, 256);
  prep_w<<<256, 256, 0, stream>>>(w3, wt3, 256, 256, 256, 256);
  prep_w<<<(16 * 256 + 255) / 256, 256, 0, stream>>>(w4, wt4, 256, 3, 256, 16);

  liif_main<<<Q * 4 / R, 256, 0, stream>>>(featT, wt0, wt1, wt2, wt3, wt4,
                                           b0, b1, b2, b3, b4, (float*)d_out);
}